// Round 21
// baseline (14.671 us; speedup 1.0000x reference)
//
#include <hip/hip_runtime.h>
#include <limits.h>

// BKT: B=4096 students, T=512 timesteps, K=2048 skills.
// R21: quad-interleaved walk. R15's dual-interleave was the session's one
// confirmed win (-1.2us) => walk latency is NOT fully TLP-hidden; this takes
// the same lever one notch further. BLK=128, TPT=4, one student/block:
//  - each thread walks 4 chains in ONE loop (4 independent ds_read streams);
//    wave walk exposure ~E[max 256 lens] vs E[max 128] (~4.5 vs 4.2 hops)
//    while serving 2x outputs -> per-output exposed latency ~halves.
//  - all walk state in NAMED SCALARS (R17's 4-chain attempt spilled via
//    register arrays, rule #20); ~50 VGPR, launch_bounds(128,8) pins <=64
//    -> 16 blocks/CU x 2 waves = 32 waves/CU; LDS 10KB x 16 = 160KB exactly.
// Kept from R15/R20: direct-mapped 2048 heads, packed nodes {resp,prev},
// min1/min2 capture (rescan only rank>=3), k0 gathers pre-walk, lazy t/g/s,
// 2 barriers, coalesced loads/stores (wave = 64 consecutive t per u).

#define BKT_B 4096
#define BKT_T 512
#define BKT_K 2048
#define BLK   128
#define PTR_END 0x3FF

__device__ __forceinline__ float bkt_update(float p, int rbit, float ss,
                                            float gg, float tt) {
  float num, den;
  if (rbit) {                // correct response
    num = p * (1.0f - ss);
    den = num + (1.0f - p) * gg;
  } else {                   // incorrect response
    num = p * ss;
    den = num + (1.0f - p) * (1.0f - gg);
  }
  const float q = num / den; // Bayesian posterior
  return q + (1.0f - q) * tt;// learning transition
}

// rare rank>=3 tail: ordered rescan of one chain (LDS node table)
__device__ __forceinline__ float bkt_rescan(const int* node_s, int head, int t,
                                            int cur, int rank, float p,
                                            float ss, float gg, float tt) {
  for (int rd = 2; rd < rank; ++rd) {
    int best = INT_MAX, bestnode = 0;
    for (int j = head; j >= 0; ) {
      const int nd = node_s[j];
      if (j < t && j > cur && j < best) { best = j; bestnode = nd; }
      const int nx = nd & PTR_END;
      j = (nx == PTR_END) ? -1 : nx;
    }
    p = bkt_update(p, (bestnode >> 10) & 1, ss, gg, tt);
    cur = best;
  }
  return p;
}

__global__ __launch_bounds__(BLK, 8) void bkt_kernel(
    const int* __restrict__ skills,
    const float* __restrict__ resp,
    const float* __restrict__ k0,
    const float* __restrict__ tp,
    const float* __restrict__ gp,
    const float* __restrict__ sp,
    float* __restrict__ out) {
  __shared__ int head_s[BKT_K];  // 8KB direct-mapped: last arrival, -1 empty
  __shared__ int node_s[BKT_T];  // 2KB packed {resp bit, prev ptr}

  const int b = blockIdx.x;
  const int base = b * BKT_T;
  const int tid = threadIdx.x;
  const int t0 = tid;
  const int t1 = tid + BLK;
  const int t2 = tid + 2 * BLK;
  const int t3 = tid + 3 * BLK;

  // coalesced row loads (wave reads 64 consecutive t's per u)
  const int   sk0 = skills[base + t0];
  const int   sk1 = skills[base + t1];
  const int   sk2 = skills[base + t2];
  const int   sk3 = skills[base + t3];
  const float rr0 = resp[base + t0];
  const float rr1 = resp[base + t1];
  const float rr2 = resp[base + t2];
  const float rr3 = resp[base + t3];
  // k0 gathers issued early: latency hides under init/build/barriers
  const float k00 = k0[sk0];
  const float k01 = k0[sk1];
  const float k02 = k0[sk2];
  const float k03 = k0[sk3];

  // head init: 2048 ints / 128 threads = four int4 stores
  {
    int4* h4 = (int4*)head_s;
    h4[tid] = make_int4(-1, -1, -1, -1);
    h4[tid + BLK] = make_int4(-1, -1, -1, -1);
    h4[tid + 2 * BLK] = make_int4(-1, -1, -1, -1);
    h4[tid + 3 * BLK] = make_int4(-1, -1, -1, -1);
  }
  __syncthreads();

  // build per-skill linked lists (arrival order arbitrary)
  {
    const int o0 = atomicExch(&head_s[sk0], t0);
    node_s[t0] = ((o0 < 0) ? PTR_END : o0) | ((rr0 > 0.5f ? 1 : 0) << 10);
    const int o1 = atomicExch(&head_s[sk1], t1);
    node_s[t1] = ((o1 < 0) ? PTR_END : o1) | ((rr1 > 0.5f ? 1 : 0) << 10);
    const int o2 = atomicExch(&head_s[sk2], t2);
    node_s[t2] = ((o2 < 0) ? PTR_END : o2) | ((rr2 > 0.5f ? 1 : 0) << 10);
    const int o3 = atomicExch(&head_s[sk3], t3);
    node_s[t3] = ((o3 < 0) ? PTR_END : o3) | ((rr3 > 0.5f ? 1 : 0) << 10);
  }
  __syncthreads();

  // quad-interleaved walk: 4 independent chains advance per iteration
  const int head0 = head_s[sk0];
  const int head1 = head_s[sk1];
  const int head2 = head_s[sk2];
  const int head3 = head_s[sk3];
  int j0 = head0, j1 = head1, j2 = head2, j3 = head3;
  int r0 = 0, r1 = 0, r2 = 0, r3 = 0;
  int a0 = INT_MAX, b0 = INT_MAX, an0 = 0, bn0 = 0;
  int a1 = INT_MAX, b1 = INT_MAX, an1 = 0, bn1 = 0;
  int a2 = INT_MAX, b2 = INT_MAX, an2 = 0, bn2 = 0;
  int a3 = INT_MAX, b3 = INT_MAX, an3 = 0, bn3 = 0;
  while ((j0 >= 0) || (j1 >= 0) || (j2 >= 0) || (j3 >= 0)) {
    if (j0 >= 0) {
      const int nd = node_s[j0];
      if (j0 < t0) {
        ++r0;
        if (j0 < a0)      { b0 = a0; bn0 = an0; a0 = j0; an0 = nd; }
        else if (j0 < b0) { b0 = j0; bn0 = nd; }
      }
      const int nx = nd & PTR_END;
      j0 = (nx == PTR_END) ? -1 : nx;
    }
    if (j1 >= 0) {
      const int nd = node_s[j1];
      if (j1 < t1) {
        ++r1;
        if (j1 < a1)      { b1 = a1; bn1 = an1; a1 = j1; an1 = nd; }
        else if (j1 < b1) { b1 = j1; bn1 = nd; }
      }
      const int nx = nd & PTR_END;
      j1 = (nx == PTR_END) ? -1 : nx;
    }
    if (j2 >= 0) {
      const int nd = node_s[j2];
      if (j2 < t2) {
        ++r2;
        if (j2 < a2)      { b2 = a2; bn2 = an2; a2 = j2; an2 = nd; }
        else if (j2 < b2) { b2 = j2; bn2 = nd; }
      }
      const int nx = nd & PTR_END;
      j2 = (nx == PTR_END) ? -1 : nx;
    }
    if (j3 >= 0) {
      const int nd = node_s[j3];
      if (j3 < t3) {
        ++r3;
        if (j3 < a3)      { b3 = a3; bn3 = an3; a3 = j3; an3 = nd; }
        else if (j3 < b3) { b3 = j3; bn3 = nd; }
      }
      const int nx = nd & PTR_END;
      j3 = (nx == PTR_END) ? -1 : nx;
    }
  }

  // replays (lazy t/g/s; rescan only rank>=3, ~0.3% of lanes)
  float p0 = k00;
  if (r0 > 0) {
    const float ss = sp[sk0], gg = gp[sk0], tt = tp[sk0];
    p0 = bkt_update(p0, (an0 >> 10) & 1, ss, gg, tt);
    if (r0 > 1) {
      p0 = bkt_update(p0, (bn0 >> 10) & 1, ss, gg, tt);
      if (r0 > 2) p0 = bkt_rescan(node_s, head0, t0, b0, r0, p0, ss, gg, tt);
    }
  }
  out[base + t0] = p0;

  float p1 = k01;
  if (r1 > 0) {
    const float ss = sp[sk1], gg = gp[sk1], tt = tp[sk1];
    p1 = bkt_update(p1, (an1 >> 10) & 1, ss, gg, tt);
    if (r1 > 1) {
      p1 = bkt_update(p1, (bn1 >> 10) & 1, ss, gg, tt);
      if (r1 > 2) p1 = bkt_rescan(node_s, head1, t1, b1, r1, p1, ss, gg, tt);
    }
  }
  out[base + t1] = p1;

  float p2 = k02;
  if (r2 > 0) {
    const float ss = sp[sk2], gg = gp[sk2], tt = tp[sk2];
    p2 = bkt_update(p2, (an2 >> 10) & 1, ss, gg, tt);
    if (r2 > 1) {
      p2 = bkt_update(p2, (bn2 >> 10) & 1, ss, gg, tt);
      if (r2 > 2) p2 = bkt_rescan(node_s, head2, t2, b2, r2, p2, ss, gg, tt);
    }
  }
  out[base + t2] = p2;

  float p3 = k03;
  if (r3 > 0) {
    const float ss = sp[sk3], gg = gp[sk3], tt = tp[sk3];
    p3 = bkt_update(p3, (an3 >> 10) & 1, ss, gg, tt);
    if (r3 > 1) {
      p3 = bkt_update(p3, (bn3 >> 10) & 1, ss, gg, tt);
      if (r3 > 2) p3 = bkt_rescan(node_s, head3, t3, b3, r3, p3, ss, gg, tt);
    }
  }
  out[base + t3] = p3;
}

extern "C" void kernel_launch(void* const* d_in, const int* in_sizes, int n_in,
                              void* d_out, int out_size, void* d_ws, size_t ws_size,
                              hipStream_t stream) {
  const int*   skills = (const int*)d_in[0];
  const float* resp   = (const float*)d_in[1];
  const float* k0     = (const float*)d_in[2];
  const float* tp     = (const float*)d_in[3];
  const float* gp     = (const float*)d_in[4];
  const float* sp     = (const float*)d_in[5];
  float* out = (float*)d_out;

  bkt_kernel<<<BKT_B, BLK, 0, stream>>>(skills, resp, k0, tp, gp, sp, out);
}

// Round 22
// 13.957 us; speedup vs baseline: 1.0512x; 1.0512x over previous
//
#include <hip/hip_runtime.h>
#include <limits.h>

// BKT: B=4096 students, T=512 timesteps, K=2048 skills.
// R22 = R20/R15 verbatim (session best, 13.92us, reproduced twice).
// R21's quad-interleave regressed (14.67): walk-loop issue doubled (union
// of 4 trip counts) for marginal exposure gain; interleave lever peaks at
// depth 2. Plateau decomposition (all components attacked >=2x, R1-R21):
// launch ~2.3us | streaming ~2.6us | scattered gathers ~2-3us (lazy = best)
// | LDS build+walk latency ~4-5us (dual-interleave = only confirmed win)
// | barriers/issue ~2us. Latency-bound irregular chase at full 32 waves/CU;
// no counter-supported lever remains inside a single-kernel design.
//  - one block per student, 256 thr, t0=tid, t1=tid+256;
//  - direct-mapped 2048-entry head table + packed nodes {resp bit, prev};
//  - dual-chain interleaved walk, min1/min2 capture -> rescan only rank>=3;
//  - k0 gathers pre-walk, t/g/s gathers lazy (rank>0 lanes only);
//  - LDS 10KB, launch_bounds(256,8) -> 8 blocks/CU = 32 waves/CU.

#define BKT_B 4096
#define BKT_T 512
#define BKT_K 2048
#define BLK   256
#define PTR_END 0x3FF

__device__ __forceinline__ float bkt_update(float p, int rbit, float ss,
                                            float gg, float tt) {
  float num, den;
  if (rbit) {                // correct response
    num = p * (1.0f - ss);
    den = num + (1.0f - p) * gg;
  } else {                   // incorrect response
    num = p * ss;
    den = num + (1.0f - p) * (1.0f - gg);
  }
  const float q = num / den; // Bayesian posterior
  return q + (1.0f - q) * tt;// learning transition
}

__global__ __launch_bounds__(BLK, 8) void bkt_kernel(
    const int* __restrict__ skills,
    const float* __restrict__ resp,
    const float* __restrict__ k0,
    const float* __restrict__ tp,
    const float* __restrict__ gp,
    const float* __restrict__ sp,
    float* __restrict__ out) {
  __shared__ int head_s[BKT_K];  // 8KB direct-mapped: last arrival, -1 empty
  __shared__ int node_s[BKT_T];  // 2KB packed {resp bit, prev ptr}

  const int b = blockIdx.x;
  const int base = b * BKT_T;
  const int tid = threadIdx.x;
  const int t0 = tid;
  const int t1 = tid + BLK;

  // coalesced row loads; k0 gathers issued early (hide under init/build)
  const int   sk0 = skills[base + t0];
  const int   sk1 = skills[base + t1];
  const float rr0 = resp[base + t0];
  const float rr1 = resp[base + t1];
  const float k00 = k0[sk0];
  const float k01 = k0[sk1];

  // head init: 2048 ints = two int4 stores per thread
  {
    int4* h4 = (int4*)head_s;
    h4[tid] = make_int4(-1, -1, -1, -1);
    h4[tid + BLK] = make_int4(-1, -1, -1, -1);
  }
  __syncthreads();

  // build per-skill linked lists (arrival order arbitrary)
  {
    const int old0 = atomicExch(&head_s[sk0], t0);
    node_s[t0] = ((old0 < 0) ? PTR_END : old0) | ((rr0 > 0.5f ? 1 : 0) << 10);
    const int old1 = atomicExch(&head_s[sk1], t1);
    node_s[t1] = ((old1 < 0) ? PTR_END : old1) | ((rr1 > 0.5f ? 1 : 0) << 10);
  }
  __syncthreads();

  // dual-chain interleaved walk: both timesteps' chains advance together
  const int head0 = head_s[sk0];
  const int head1 = head_s[sk1];
  int j0 = head0, j1 = head1;
  int rank0 = 0, rank1 = 0;
  int a0 = INT_MAX, b0 = INT_MAX, an0 = 0, bn0 = 0;  // min1/min2 (t0)
  int a1 = INT_MAX, b1 = INT_MAX, an1 = 0, bn1 = 0;  // min1/min2 (t1)
  while ((j0 >= 0) || (j1 >= 0)) {
    if (j0 >= 0) {
      const int nd = node_s[j0];
      if (j0 < t0) {
        ++rank0;
        if (j0 < a0)      { b0 = a0; bn0 = an0; a0 = j0; an0 = nd; }
        else if (j0 < b0) { b0 = j0; bn0 = nd; }
      }
      const int nx = nd & PTR_END;
      j0 = (nx == PTR_END) ? -1 : nx;
    }
    if (j1 >= 0) {
      const int nd = node_s[j1];
      if (j1 < t1) {
        ++rank1;
        if (j1 < a1)      { b1 = a1; bn1 = an1; a1 = j1; an1 = nd; }
        else if (j1 < b1) { b1 = j1; bn1 = nd; }
      }
      const int nx = nd & PTR_END;
      j1 = (nx == PTR_END) ? -1 : nx;
    }
  }

  // ---- t0 replay ----
  float p0 = k00;
  if (rank0 > 0) {
    const float ss = sp[sk0];
    const float gg = gp[sk0];
    const float tt = tp[sk0];
    p0 = bkt_update(p0, (an0 >> 10) & 1, ss, gg, tt);
    if (rank0 > 1) {
      p0 = bkt_update(p0, (bn0 >> 10) & 1, ss, gg, tt);
      int cur = b0;
      for (int rd = 2; rd < rank0; ++rd) {   // rank>=3 only (~0.3% lanes)
        int best = INT_MAX, bestnode = 0;
        for (int j = head0; j >= 0; ) {
          const int nd = node_s[j];
          if (j < t0 && j > cur && j < best) { best = j; bestnode = nd; }
          const int nx = nd & PTR_END;
          j = (nx == PTR_END) ? -1 : nx;
        }
        p0 = bkt_update(p0, (bestnode >> 10) & 1, ss, gg, tt);
        cur = best;
      }
    }
  }
  out[base + t0] = p0;                 // emit pre-update mastery

  // ---- t1 replay ----
  float p1 = k01;
  if (rank1 > 0) {
    const float ss = sp[sk1];
    const float gg = gp[sk1];
    const float tt = tp[sk1];
    p1 = bkt_update(p1, (an1 >> 10) & 1, ss, gg, tt);
    if (rank1 > 1) {
      p1 = bkt_update(p1, (bn1 >> 10) & 1, ss, gg, tt);
      int cur = b1;
      for (int rd = 2; rd < rank1; ++rd) {
        int best = INT_MAX, bestnode = 0;
        for (int j = head1; j >= 0; ) {
          const int nd = node_s[j];
          if (j < t1 && j > cur && j < best) { best = j; bestnode = nd; }
          const int nx = nd & PTR_END;
          j = (nx == PTR_END) ? -1 : nx;
        }
        p1 = bkt_update(p1, (bestnode >> 10) & 1, ss, gg, tt);
        cur = best;
      }
    }
  }
  out[base + t1] = p1;                 // emit pre-update mastery
}

extern "C" void kernel_launch(void* const* d_in, const int* in_sizes, int n_in,
                              void* d_out, int out_size, void* d_ws, size_t ws_size,
                              hipStream_t stream) {
  const int*   skills = (const int*)d_in[0];
  const float* resp   = (const float*)d_in[1];
  const float* k0     = (const float*)d_in[2];
  const float* tp     = (const float*)d_in[3];
  const float* gp     = (const float*)d_in[4];
  const float* sp     = (const float*)d_in[5];
  float* out = (float*)d_out;

  bkt_kernel<<<BKT_B, BLK, 0, stream>>>(skills, resp, k0, tp, gp, sp, out);
}